// Round 1
// baseline (348.126 us; speedup 1.0000x reference)
//
#include <hip/hip_runtime.h>
#include <hip/hip_bf16.h>
#include <math.h>

#define N 8192
#define D 1024
#define TILE 128
#define BK 32

typedef __bf16 bf16_t;
typedef bf16_t bf16x4 __attribute__((ext_vector_type(4)));
typedef bf16_t bf16x8 __attribute__((ext_vector_type(8)));
typedef float f32x4 __attribute__((ext_vector_type(4)));

// ---------------------------------------------------------------------------
// Kernel 1: L2-normalize each row of the fp32 embeddings, cast to bf16.
// One block (256 threads) per row; each thread handles 4 floats.
// ---------------------------------------------------------------------------
__global__ __launch_bounds__(256) void norm_cast(const float* __restrict__ in,
                                                 bf16_t* __restrict__ out) {
    const int row = blockIdx.x;
    const int tid = threadIdx.x;
    const float4 v = ((const float4*)(in + (size_t)row * D))[tid];
    float ss = v.x * v.x + v.y * v.y + v.z * v.z + v.w * v.w;
    #pragma unroll
    for (int off = 32; off >= 1; off >>= 1) ss += __shfl_xor(ss, off, 64);
    __shared__ float red[4];
    const int wave = tid >> 6, lane = tid & 63;
    if (lane == 0) red[wave] = ss;
    __syncthreads();
    const float tot = red[0] + red[1] + red[2] + red[3];
    const float scale = 1.0f / fmaxf(sqrtf(tot), 1e-12f);
    bf16x4 o;
    o[0] = (bf16_t)(v.x * scale);
    o[1] = (bf16_t)(v.y * scale);
    o[2] = (bf16_t)(v.z * scale);
    o[3] = (bf16_t)(v.w * scale);
    ((bf16x4*)(out + (size_t)row * D))[tid] = o;
}

// ---------------------------------------------------------------------------
// Kernel 2: fused  C = E·E^T / T  ->  exp  ->  masked row sums (atomics).
// m97 structure: 128x128 tile, BK=32, global_load_lds width=16 staging,
// 4 waves in 2x2, each wave 64x64 via 4x4 grid of 16x16x32 bf16 MFMAs.
// ---------------------------------------------------------------------------
__global__ __launch_bounds__(256) void gemm_fused(const bf16_t* __restrict__ E,
                                                  const int* __restrict__ labels,
                                                  float* __restrict__ sumExp,
                                                  float* __restrict__ posSum) {
    __shared__ bf16_t As[TILE * BK];   // 8 KB, row-major [128][32]
    __shared__ bf16_t Bs[TILE * BK];   // 8 KB
    __shared__ int labR[TILE], labC[TILE];

    const int tid     = threadIdx.x;
    const int wave    = tid >> 6;
    const int lane    = tid & 63;
    const int q       = lane >> 4;    // quad within wave (0..3)
    const int lr      = lane & 15;
    const int waveRow = wave >> 1;    // 2x2 wave grid
    const int waveCol = wave & 1;
    const int rowStart = blockIdx.y * TILE;
    const int colStart = blockIdx.x * TILE;

    if (tid < TILE) labR[tid] = labels[rowStart + tid];
    else            labC[tid - TILE] = labels[colStart + (tid - TILE)];

    f32x4 acc[4][4];
    #pragma unroll
    for (int i = 0; i < 4; ++i)
        #pragma unroll
        for (int j = 0; j < 4; ++j)
            acc[i][j] = {0.f, 0.f, 0.f, 0.f};

    const char* baseA = (const char*)(E + (size_t)rowStart * D);
    const char* baseB = (const char*)(E + (size_t)colStart * D);

    for (int kk = 0; kk < D; kk += BK) {
        // Stage A,B tiles: 128 rows x 64 B = 512 16-byte units, 2 passes of 256 lanes.
        // LDS dest is wave-uniform base; HW scatters lane*16.
        #pragma unroll
        for (int p = 0; p < 2; ++p) {
            const int u   = p * 256 + tid;       // 16B-unit index into tile
            const int r   = u >> 2;              // row (4 units per 64B row)
            const int inb = (u & 3) * 16;        // byte offset within row
            const char* ga = baseA + (size_t)r * (D * 2) + kk * 2 + inb;
            const char* gb = baseB + (size_t)r * (D * 2) + kk * 2 + inb;
            char* la = (char*)As + (p * 256 + wave * 64) * 16;
            char* lb = (char*)Bs + (p * 256 + wave * 64) * 16;
            __builtin_amdgcn_global_load_lds(
                (const __attribute__((address_space(1))) void*)ga,
                (__attribute__((address_space(3))) void*)la, 16, 0, 0);
            __builtin_amdgcn_global_load_lds(
                (const __attribute__((address_space(1))) void*)gb,
                (__attribute__((address_space(3))) void*)lb, 16, 0, 0);
        }
        __syncthreads();   // compiler emits vmcnt(0) drain before s_barrier

        bf16x8 af[4], bfr[4];
        #pragma unroll
        for (int ri = 0; ri < 4; ++ri)
            af[ri] = *(const bf16x8*)&As[(waveRow * 64 + ri * 16 + lr) * BK + q * 8];
        #pragma unroll
        for (int ci = 0; ci < 4; ++ci)
            bfr[ci] = *(const bf16x8*)&Bs[(waveCol * 64 + ci * 16 + lr) * BK + q * 8];
        #pragma unroll
        for (int ri = 0; ri < 4; ++ri)
            #pragma unroll
            for (int ci = 0; ci < 4; ++ci)
                acc[ri][ci] = __builtin_amdgcn_mfma_f32_16x16x32_bf16(
                    af[ri], bfr[ci], acc[ri][ci], 0, 0, 0);
        __syncthreads();
    }

    // Epilogue: C/D layout col=lane&15, row=q*4+e (verified m89/m91).
    const float invT = 1.0f / 0.07f;
    #pragma unroll
    for (int ri = 0; ri < 4; ++ri) {
        #pragma unroll
        for (int e = 0; e < 4; ++e) {
            const int rloc = waveRow * 64 + ri * 16 + q * 4 + e;
            const int gi   = rowStart + rloc;
            const int li   = labR[rloc];
            float s_all = 0.f, s_pos = 0.f;
            #pragma unroll
            for (int ci = 0; ci < 4; ++ci) {
                const int cloc = waveCol * 64 + ci * 16 + lr;
                const int gj   = colStart + cloc;
                const float v  = __expf(acc[ri][ci][e] * invT);
                s_all += v;
                if (labC[cloc] == li && gi != gj) s_pos += v;
            }
            // reduce across the 16 cols held by the quad (lane bits 0..3)
            #pragma unroll
            for (int off = 1; off < 16; off <<= 1) {
                s_all += __shfl_xor(s_all, off, 64);
                s_pos += __shfl_xor(s_pos, off, 64);
            }
            if (lr == 0) {
                atomicAdd(&sumExp[gi], s_all);
                atomicAdd(&posSum[gi], s_pos);
            }
        }
    }
}

// ---------------------------------------------------------------------------
// Kernel 3: loss_i = log(sumExp_i) - log(posSum_i); out = mean(loss).
// ---------------------------------------------------------------------------
__global__ __launch_bounds__(256) void finalize(const float* __restrict__ sumExp,
                                                const float* __restrict__ posSum,
                                                float* __restrict__ out) {
    const int tid = threadIdx.x;
    float s = 0.f;
    for (int i = tid; i < N; i += 256)
        s += logf(sumExp[i]) - logf(posSum[i]);
    #pragma unroll
    for (int off = 32; off >= 1; off >>= 1) s += __shfl_xor(s, off, 64);
    __shared__ float red[4];
    if ((tid & 63) == 0) red[tid >> 6] = s;
    __syncthreads();
    if (tid == 0) out[0] = (red[0] + red[1] + red[2] + red[3]) / (float)N;
}

extern "C" void kernel_launch(void* const* d_in, const int* in_sizes, int n_in,
                              void* d_out, int out_size, void* d_ws, size_t ws_size,
                              hipStream_t stream) {
    const float* emb    = (const float*)d_in[0];
    const int*   labels = (const int*)d_in[1];
    float* out = (float*)d_out;

    // ws layout: [sumExp: N floats][posSum: N floats][EN: N*D bf16]
    float*  sumExp = (float*)d_ws;
    float*  posSum = sumExp + N;
    bf16_t* EN     = (bf16_t*)((char*)d_ws + (size_t)2 * N * sizeof(float));

    hipMemsetAsync(d_ws, 0, (size_t)2 * N * sizeof(float), stream);

    norm_cast<<<N, 256, 0, stream>>>(emb, EN);

    dim3 grid(N / TILE, N / TILE);
    gemm_fused<<<grid, 256, 0, stream>>>(EN, labels, sumExp, posSum);

    finalize<<<1, 256, 0, stream>>>(sumExp, posSum, out);
}

// Round 2
// 217.346 us; speedup vs baseline: 1.6017x; 1.6017x over previous
//
#include <hip/hip_runtime.h>
#include <hip/hip_bf16.h>
#include <math.h>

#define N 8192
#define D 1024
#define TILE 128
#define BK 32
#define NTILES (N / TILE)                 // 64
#define NBLOCKS (NTILES * (NTILES + 1) / 2)  // 2080 lower-tri tiles

typedef __bf16 bf16_t;
typedef bf16_t bf16x4 __attribute__((ext_vector_type(4)));
typedef bf16_t bf16x8 __attribute__((ext_vector_type(8)));
typedef float f32x4 __attribute__((ext_vector_type(4)));

// ---------------------------------------------------------------------------
// Kernel 1: L2-normalize each row of the fp32 embeddings, cast to bf16.
// ---------------------------------------------------------------------------
__global__ __launch_bounds__(256) void norm_cast(const float* __restrict__ in,
                                                 bf16_t* __restrict__ out) {
    const int row = blockIdx.x;
    const int tid = threadIdx.x;
    const float4 v = ((const float4*)(in + (size_t)row * D))[tid];
    float ss = v.x * v.x + v.y * v.y + v.z * v.z + v.w * v.w;
    #pragma unroll
    for (int off = 32; off >= 1; off >>= 1) ss += __shfl_xor(ss, off, 64);
    __shared__ float red[4];
    const int wave = tid >> 6, lane = tid & 63;
    if (lane == 0) red[wave] = ss;
    __syncthreads();
    const float tot = red[0] + red[1] + red[2] + red[3];
    const float scale = 1.0f / fmaxf(sqrtf(tot), 1e-12f);
    bf16x4 o;
    o[0] = (bf16_t)(v.x * scale);
    o[1] = (bf16_t)(v.y * scale);
    o[2] = (bf16_t)(v.z * scale);
    o[3] = (bf16_t)(v.w * scale);
    ((bf16x4*)(out + (size_t)row * D))[tid] = o;
}

// ---------------------------------------------------------------------------
// Kernel 2: fused symmetric  C = E·E^T / T -> exp -> masked row+col sums.
// Lower-triangular tile grid (2080 blocks). Off-diagonal tiles contribute
// row sums AND column sums (sim is exactly symmetric: same bf16 operand).
// LDS uses an XOR swizzle on the 16B unit column (u ^ ((row>>1)&3)) so the
// MFMA frag reads hit all 8 bank-groups (2-way only, free per m136), while
// global_load_lds staging stays wave-uniform (we permute the global source
// address instead, still 64B-coalesced).
// ---------------------------------------------------------------------------
__global__ __launch_bounds__(256) void gemm_fused(const bf16_t* __restrict__ E,
                                                  const int* __restrict__ labels,
                                                  float* __restrict__ sumExp,
                                                  float* __restrict__ posSum) {
    __shared__ bf16_t As[TILE * BK];   // 8 KB, swizzled [128][4 units of 16B]
    __shared__ bf16_t Bs[TILE * BK];   // 8 KB
    __shared__ int labR[TILE], labC[TILE];

    // triangular decode: b -> (ti >= tj)
    const int b = blockIdx.x;
    int ti = (int)((sqrtf(8.0f * (float)b + 1.0f) - 1.0f) * 0.5f);
    while ((ti + 1) * (ti + 2) / 2 <= b) ++ti;
    while (ti * (ti + 1) / 2 > b) --ti;
    const int tj = b - ti * (ti + 1) / 2;
    const bool isDiag = (ti == tj);

    const int tid     = threadIdx.x;
    const int wave    = tid >> 6;
    const int lane    = tid & 63;
    const int q       = lane >> 4;    // quad within wave (0..3)
    const int lr      = lane & 15;
    const int waveRow = wave >> 1;    // 2x2 wave grid
    const int waveCol = wave & 1;
    const int rowStart = ti * TILE;
    const int colStart = tj * TILE;

    if (tid < TILE) labR[tid] = labels[rowStart + tid];
    else            labC[tid - TILE] = labels[colStart + (tid - TILE)];

    f32x4 acc[4][4];
    #pragma unroll
    for (int i = 0; i < 4; ++i)
        #pragma unroll
        for (int j = 0; j < 4; ++j)
            acc[i][j] = {0.f, 0.f, 0.f, 0.f};

    const char* baseA = (const char*)(E + (size_t)rowStart * D);
    const char* baseB = (const char*)(E + (size_t)colStart * D);

    // frag-read swizzled unit for this lane (independent of ri/ci: offsets are
    // multiples of 8 rows, so (row>>1)&3 == (lr>>1)&3)
    const int runit = q ^ ((lr >> 1) & 3);

    for (int kk = 0; kk < D; kk += BK) {
        #pragma unroll
        for (int p = 0; p < 2; ++p) {
            const int u  = p * 256 + tid;                 // LDS 16B slot
            const int r  = u >> 2;                        // tile row
            const int uc = (u & 3) ^ ((r >> 1) & 3);      // swizzled global col unit
            const char* ga = baseA + (size_t)r * (D * 2) + kk * 2 + uc * 16;
            const char* gb = baseB + (size_t)r * (D * 2) + kk * 2 + uc * 16;
            char* la = (char*)As + (p * 256 + wave * 64) * 16;
            char* lb = (char*)Bs + (p * 256 + wave * 64) * 16;
            __builtin_amdgcn_global_load_lds(
                (const __attribute__((address_space(1))) void*)ga,
                (__attribute__((address_space(3))) void*)la, 16, 0, 0);
            __builtin_amdgcn_global_load_lds(
                (const __attribute__((address_space(1))) void*)gb,
                (__attribute__((address_space(3))) void*)lb, 16, 0, 0);
        }
        __syncthreads();

        bf16x8 af[4], bfr[4];
        #pragma unroll
        for (int ri = 0; ri < 4; ++ri)
            af[ri] = *(const bf16x8*)((const char*)As +
                     (waveRow * 64 + ri * 16 + lr) * 64 + runit * 16);
        #pragma unroll
        for (int ci = 0; ci < 4; ++ci)
            bfr[ci] = *(const bf16x8*)((const char*)Bs +
                      (waveCol * 64 + ci * 16 + lr) * 64 + runit * 16);
        #pragma unroll
        for (int ri = 0; ri < 4; ++ri)
            #pragma unroll
            for (int ci = 0; ci < 4; ++ci)
                acc[ri][ci] = __builtin_amdgcn_mfma_f32_16x16x32_bf16(
                    af[ri], bfr[ci], acc[ri][ci], 0, 0, 0);
        __syncthreads();
    }

    // Epilogue. C/D layout: col=lane&15, row=q*4+e (m89/m91).
    const float invT = 1.0f / 0.07f;
    float colAll[4] = {0.f, 0.f, 0.f, 0.f};
    float colPos[4] = {0.f, 0.f, 0.f, 0.f};
    #pragma unroll
    for (int ri = 0; ri < 4; ++ri) {
        #pragma unroll
        for (int e = 0; e < 4; ++e) {
            const int rloc = waveRow * 64 + ri * 16 + q * 4 + e;
            const int gi   = rowStart + rloc;
            const int li   = labR[rloc];
            float s_all = 0.f, s_pos = 0.f;
            #pragma unroll
            for (int ci = 0; ci < 4; ++ci) {
                const int cloc = waveCol * 64 + ci * 16 + lr;
                const int gj   = colStart + cloc;
                const float v  = __expf(acc[ri][ci][e] * invT);
                const bool same = (labC[cloc] == li);
                s_all += v;
                if (same && gi != gj) s_pos += v;
                if (!isDiag) {          // wave-uniform branch
                    colAll[ci] += v;    // gi != gj guaranteed off-diagonal
                    if (same) colPos[ci] += v;
                }
            }
            #pragma unroll
            for (int off = 1; off < 16; off <<= 1) {
                s_all += __shfl_xor(s_all, off, 64);
                s_pos += __shfl_xor(s_pos, off, 64);
            }
            if (lr == 0) {
                atomicAdd(&sumExp[gi], s_all);
                atomicAdd(&posSum[gi], s_pos);
            }
        }
    }
    if (!isDiag) {
        #pragma unroll
        for (int ci = 0; ci < 4; ++ci) {
            float a = colAll[ci], p = colPos[ci];
            a += __shfl_xor(a, 16, 64);  a += __shfl_xor(a, 32, 64);
            p += __shfl_xor(p, 16, 64);  p += __shfl_xor(p, 32, 64);
            if (q == 0) {
                const int gj = colStart + waveCol * 64 + ci * 16 + lr;
                atomicAdd(&sumExp[gj], a);
                atomicAdd(&posSum[gj], p);
            }
        }
    }
}

// ---------------------------------------------------------------------------
// Kernel 3: loss_i = log(sumExp_i / posSum_i); out = mean(loss).
// ---------------------------------------------------------------------------
__global__ __launch_bounds__(1024) void finalize(const float* __restrict__ sumExp,
                                                 const float* __restrict__ posSum,
                                                 float* __restrict__ out) {
    const int tid = threadIdx.x;
    float s = 0.f;
    #pragma unroll
    for (int i = tid; i < N; i += 1024)
        s += __logf(sumExp[i] / posSum[i]);
    #pragma unroll
    for (int off = 32; off >= 1; off >>= 1) s += __shfl_xor(s, off, 64);
    __shared__ float red[16];
    if ((tid & 63) == 0) red[tid >> 6] = s;
    __syncthreads();
    if (tid == 0) {
        float t = 0.f;
        #pragma unroll
        for (int i = 0; i < 16; ++i) t += red[i];
        out[0] = t / (float)N;
    }
}

extern "C" void kernel_launch(void* const* d_in, const int* in_sizes, int n_in,
                              void* d_out, int out_size, void* d_ws, size_t ws_size,
                              hipStream_t stream) {
    const float* emb    = (const float*)d_in[0];
    const int*   labels = (const int*)d_in[1];
    float* out = (float*)d_out;

    // ws layout: [sumExp: N floats][posSum: N floats][EN: N*D bf16]
    float*  sumExp = (float*)d_ws;
    float*  posSum = sumExp + N;
    bf16_t* EN     = (bf16_t*)((char*)d_ws + (size_t)2 * N * sizeof(float));

    hipMemsetAsync(d_ws, 0, (size_t)2 * N * sizeof(float), stream);

    norm_cast<<<N, 256, 0, stream>>>(emb, EN);

    gemm_fused<<<NBLOCKS, 256, 0, stream>>>(EN, labels, sumExp, posSum);

    finalize<<<1, 1024, 0, stream>>>(sumExp, posSum, out);
}